// Round 1
// baseline (1387.460 us; speedup 1.0000x reference)
//
#include <hip/hip_runtime.h>

#define NA   100000
#define NP   1600000
#define FDIM 128
#define NRBF 32
#define LN2  0.69314718055994530942f

typedef __attribute__((ext_vector_type(8))) short short8;  // 8 bf16 = 4 VGPRs
typedef __attribute__((ext_vector_type(4))) float f32x4;

// ShiftedSoftplus via hardware exp2/log2:
// softplus(x)-ln2 = max(x,0) + ln2*(log2(1 + 2^(-|x|*log2e)) - 1)
__device__ __forceinline__ float ssp_f(float v) {
    float e = __builtin_amdgcn_exp2f(fabsf(v) * -1.4426950408889634f);
    float l = __builtin_amdgcn_logf(1.0f + e);          // log2
    return fmaxf(v, 0.0f) + 0.6931471805599453f * (l - 1.0f);
}

// f32 -> bf16 with round-to-nearest-even
__device__ __forceinline__ short f2bf(float f) {
    union { float f; unsigned u; } v; v.f = f;
    unsigned r = v.u + 0x7FFF + ((v.u >> 16) & 1);
    return (short)(r >> 16);
}

// bf16 (as u16) -> f32
__device__ __forceinline__ float bf2f(unsigned short u) {
    union { unsigned u; float f; } v; v.u = ((unsigned)u) << 16;
    return v.f;
}

// ---------------------------------------------------------------------------
// K0: pre-transpose all weights to bf16 [n][k] in ws.
// ---------------------------------------------------------------------------
__global__ void k_prep(const float* __restrict__ Wf1, const float* __restrict__ Wf2,
                       const float* __restrict__ Wo1, const float* __restrict__ Wo2,
                       const float* __restrict__ Win,
                       short* __restrict__ Wf1T, short* __restrict__ Wf2T,
                       short* __restrict__ Wo1T, short* __restrict__ Wo2T,
                       short* __restrict__ WinT) {
    int i = blockIdx.x * 256 + threadIdx.x;          // 64 blocks -> 16384
    int n = i >> 7, k = i & 127;
    Wf2T[i] = f2bf(Wf2[k * FDIM + n]);
    Wo1T[i] = f2bf(Wo1[k * FDIM + n]);
    Wo2T[i] = f2bf(Wo2[k * FDIM + n]);
    WinT[i] = f2bf(Win[k * FDIM + n]);
    if (i < 128 * 32) {
        int n1 = i >> 5, k1 = i & 31;
        Wf1T[i] = f2bf(Wf1[k1 * FDIM + n1]);
    }
}

// ---------------------------------------------------------------------------
// K1-MFMA: h = x @ W_in (no bias), output bf16. 64 atoms / 256-thread block.
// Also computes a slice of the pair histogram (fused, hides under x staging).
// ---------------------------------------------------------------------------
__global__ __launch_bounds__(256) void k_in_proj_mfma(
        const float* __restrict__ x, const short* __restrict__ WinT,
        short* __restrict__ hB,
        const int* __restrict__ pl, int* __restrict__ count) {
    __shared__ __attribute__((aligned(16))) unsigned short XsB[64 * 136]; // 17408 B

    const int t = threadIdx.x;
    const int r0g = blockIdx.x * 64;
    const int lane = t & 63, wv = t >> 6, q = lane >> 4, ln = lane & 15;

    // fused histogram slice: NBA*1024 >= NP
    {
        int p = blockIdx.x * 1024 + t;
        #pragma unroll
        for (int i = 0; i < 4; ++i) {
            if (p < NP) atomicAdd(&count[pl[p]], 1);
            p += 256;
        }
    }

    // stage x tile -> bf16 LDS (row layout)
    #pragma unroll
    for (int i = 0; i < 4; ++i) {
        int idx = i * 256 + t;
        int row = idx >> 4, ch = idx & 15;             // 16 chunks of 8 floats
        float4 a = {0,0,0,0}, b = {0,0,0,0};
        if (r0g + row < NA) {
            const float* xp = x + (size_t)(r0g + row) * FDIM + ch * 8;
            a = *(const float4*)xp;
            b = *(const float4*)(xp + 4);
        }
        short8 s = {f2bf(a.x), f2bf(a.y), f2bf(a.z), f2bf(a.w),
                    f2bf(b.x), f2bf(b.y), f2bf(b.z), f2bf(b.w)};
        *(short8*)(XsB + row * 136 + ch * 8) = s;
    }
    __syncthreads();

    f32x4 c[8];
    #pragma unroll
    for (int tt = 0; tt < 8; ++tt) c[tt] = (f32x4){0.f, 0.f, 0.f, 0.f};
    #pragma unroll
    for (int kk = 0; kk < 4; ++kk) {
        short8 a = *(const short8*)(XsB + (16 * wv + ln) * 136 + kk * 32 + q * 8);
        #pragma unroll
        for (int tt = 0; tt < 8; ++tt) {
            short8 b = *(const short8*)(WinT + (16 * tt + ln) * FDIM + kk * 32 + q * 8);
            c[tt] = __builtin_amdgcn_mfma_f32_16x16x32_bf16(a, b, c[tt], 0, 0, 0);
        }
    }
    __syncthreads();   // XsB reads done; may overwrite with output

    #pragma unroll
    for (int tt = 0; tt < 8; ++tt)
        #pragma unroll
        for (int r = 0; r < 4; ++r)
            XsB[(16 * wv + 4 * q + r) * 136 + 16 * tt + ln] =
                (unsigned short)f2bf(c[tt][r]);
    __syncthreads();

    #pragma unroll
    for (int i = 0; i < 4; ++i) {
        int idx = i * 256 + t;
        int row = idx >> 4, ch = idx & 15;             // 16 short8 chunks/row
        if (r0g + row < NA)
            *(short8*)(hB + (size_t)(r0g + row) * FDIM + ch * 8) =
                *(const short8*)(XsB + row * 136 + ch * 8);
    }
}

// ---------------------------------------------------------------------------
// Sort pipeline: counting sort of pairs by idx_i (hist fused into K1).
// ---------------------------------------------------------------------------
__global__ __launch_bounds__(256) void k_scan1(const int* __restrict__ count,
                                               int* __restrict__ base,
                                               int* __restrict__ bsum) {
    __shared__ int sh[256];
    int i = blockIdx.x * 256 + threadIdx.x;
    int v = (i < NA) ? count[i] : 0;
    sh[threadIdx.x] = v;
    __syncthreads();
    for (int off = 1; off < 256; off <<= 1) {
        int add = (threadIdx.x >= off) ? sh[threadIdx.x - off] : 0;
        __syncthreads();
        sh[threadIdx.x] += add;
        __syncthreads();
    }
    if (i < NA) base[i] = sh[threadIdx.x] - v;     // exclusive
    if (threadIdx.x == 255) bsum[blockIdx.x] = sh[255];
}

__global__ __launch_bounds__(512) void k_scan2(int* __restrict__ bsum, int nb) {
    __shared__ int sh[512];
    int t = threadIdx.x;
    int v = (t < nb) ? bsum[t] : 0;
    sh[t] = v;
    __syncthreads();
    for (int off = 1; off < 512; off <<= 1) {
        int add = (t >= off) ? sh[t - off] : 0;
        __syncthreads();
        sh[t] += add;
        __syncthreads();
    }
    if (t < nb) bsum[t] = sh[t] - v;               // exclusive
}

__global__ void k_scan3(const int* __restrict__ bsum, int* __restrict__ base,
                        int* __restrict__ cursor) {
    int i = blockIdx.x * 256 + threadIdx.x;
    if (i < NA) {
        int b = base[i] + bsum[blockIdx.x];
        base[i]   = b;
        cursor[i] = b;
    }
}

__global__ void k_reorder(const int* __restrict__ pl, int* __restrict__ cursor,
                          int* __restrict__ perm) {
    int p = blockIdx.x * 256 + threadIdx.x;
    if (p < NP) {
        int pos = atomicAdd(&cursor[pl[p]], 1);
        perm[pos] = p;
    }
}

// ---------------------------------------------------------------------------
// K2-MFMA: fused filter network (bf16 MFMA) + gather + sorted LDS scatter.
// Phase 3 uses an LDS transpose of W_ij (bf16, cut applied) so each thread
// owns 8 contiguous channels: 1 ds_read_b128 + 1 global dwordx4 per pair-row
// (was 8 scalar dword gathers). Flush: interior slots are provably exclusive
// to this block (pairs sorted by atom) -> plain float4 stores; atomics only
// for the first/last slot.
// ---------------------------------------------------------------------------
__global__ __launch_bounds__(256) void k_pairs_mfma(
        const int*   __restrict__ perm,
        const int*   __restrict__ pl,
        const float* __restrict__ fij,
        const float* __restrict__ fcut,
        const short* __restrict__ hB,
        const short* __restrict__ Wf1T,
        const float* __restrict__ bf1,
        const short* __restrict__ Wf2T,
        const float* __restrict__ bf2,
        float* __restrict__ acc_out) {
    __shared__ float SlotAcc[64 * 132];              // 33792 B
    unsigned short* TmpB = (unsigned short*)SlotAcc; // [64][136] bf16 (alias, phase1->2)
    __shared__ __attribute__((aligned(16))) unsigned short WB[64 * 136]; // 17408 B
    __shared__ int   ajs[64], slots[64], slot_atom[64], sps_s[64];
    __shared__ float cuts[64];
    __shared__ int   nslots_s;

    const int t    = threadIdx.x;
    const int p0   = blockIdx.x * 64;
    const int lane = t & 63;
    const int wv   = t >> 6;          // wave id = m-tile
    const int q    = lane >> 4;       // quad
    const int ln   = lane & 15;

    if (t < 64) {   // exactly wave 0
        int sp = perm[p0 + t];
        int ai = pl[sp];
        sps_s[t] = sp;
        ajs[t]   = pl[NP + sp];
        cuts[t]  = fcut[sp];
        int prev = __shfl_up(ai, 1);
        bool head = (t == 0) || (ai != prev);
        unsigned long long mask = __ballot(head);
        int slot = __popcll(mask & ((2ULL << t) - 1)) - 1;
        slots[t] = slot;
        if (head) slot_atom[slot] = ai;
        if (t == 0) nslots_s = (int)__popcll(mask);
    }
    __syncthreads();

    // ---- phase 1: C1 = F @ Wf1 (A built in-reg from gathered f_ij rows) ----
    short8 aF;
    {
        const float* fr = fij + (size_t)sps_s[16 * wv + ln] * NRBF + q * 8;
        float4 f0 = *(const float4*)(fr);
        float4 f1 = *(const float4*)(fr + 4);
        aF = (short8){f2bf(f0.x), f2bf(f0.y), f2bf(f0.z), f2bf(f0.w),
                      f2bf(f1.x), f2bf(f1.y), f2bf(f1.z), f2bf(f1.w)};
    }
    f32x4 c1[8];
    #pragma unroll
    for (int tt = 0; tt < 8; ++tt) {
        short8 b = *(const short8*)(Wf1T + (16 * tt + ln) * NRBF + q * 8);
        f32x4 z = {0.f, 0.f, 0.f, 0.f};
        c1[tt] = __builtin_amdgcn_mfma_f32_16x16x32_bf16(aF, b, z, 0, 0, 0);
    }

    // ssp + bias, C-layout -> TmpB[pair][k] bf16 (A-layout for phase 2)
    #pragma unroll
    for (int tt = 0; tt < 8; ++tt) {
        float bias = bf1[16 * tt + ln];
        #pragma unroll
        for (int r = 0; r < 4; ++r) {
            float v = ssp_f(c1[tt][r] + bias);
            TmpB[(16 * wv + 4 * q + r) * 136 + 16 * tt + ln] = (unsigned short)f2bf(v);
        }
    }
    __syncthreads();

    // ---- phase 2: C2 = Tmp @ Wf2, 4 k-steps ----
    f32x4 c2[8];
    #pragma unroll
    for (int tt = 0; tt < 8; ++tt) c2[tt] = (f32x4){0.f, 0.f, 0.f, 0.f};
    #pragma unroll
    for (int kk = 0; kk < 4; ++kk) {
        short8 a = *(const short8*)(TmpB + (16 * wv + ln) * 136 + kk * 32 + q * 8);
        #pragma unroll
        for (int tt = 0; tt < 8; ++tt) {
            short8 b = *(const short8*)(Wf2T + (size_t)(16 * tt + ln) * FDIM + kk * 32 + q * 8);
            c2[tt] = __builtin_amdgcn_mfma_f32_16x16x32_bf16(a, b, c2[tt], 0, 0, 0);
        }
    }

    // ---- write W_ij = (C2 + bf2) * cut to WB (bf16, transposed access) ----
    #pragma unroll
    for (int tt = 0; tt < 8; ++tt) {
        float bias = bf2[16 * tt + ln];
        #pragma unroll
        for (int r = 0; r < 4; ++r) {
            int row = 16 * wv + 4 * q + r;
            float v = (c2[tt][r] + bias) * cuts[row];
            WB[row * 136 + 16 * tt + ln] = (unsigned short)f2bf(v);
        }
    }
    __syncthreads();   // TmpB reads done (SlotAcc may overwrite) + WB visible

    for (int i = t; i < 64 * 132; i += 256) SlotAcc[i] = 0.f;
    __syncthreads();

    // ---- phase 3: contiguous 8-channel ownership per thread ----
    {
        const int r0 = (t >> 4) * 4;     // 4 consecutive sorted pairs
        const int c0 = (t & 15) * 8;     // 8 contiguous channels
        float run[8] = {};
        int cur = slots[r0];
        #pragma unroll
        for (int r = 0; r < 4; ++r) {
            int p = r0 + r;
            int s = slots[p];
            if (s != cur) {
                #pragma unroll
                for (int j = 0; j < 8; ++j) {
                    atomicAdd(&SlotAcc[cur * 132 + c0 + j], run[j]);
                    run[j] = 0.f;
                }
                cur = s;
            }
            short8 wb = *(const short8*)(WB + p * 136 + c0);
            short8 hb = *(const short8*)(hB + (size_t)ajs[p] * FDIM + c0);
            #pragma unroll
            for (int j = 0; j < 8; ++j)
                run[j] = fmaf(bf2f((unsigned short)wb[j]),
                              bf2f((unsigned short)hb[j]), run[j]);
        }
        #pragma unroll
        for (int j = 0; j < 8; ++j)
            atomicAdd(&SlotAcc[cur * 132 + c0 + j], run[j]);
    }
    __syncthreads();

    // ---- flush: interior slots exclusive -> plain stores; edges atomic ----
    const int nslots = nslots_s;
    const int c0 = (t & 15) * 8;
    for (int s = (t >> 4); s < nslots; s += 16) {
        float* outp = acc_out + (size_t)slot_atom[s] * FDIM + c0;
        const float* src = &SlotAcc[s * 132 + c0];
        if (s == 0 || s == nslots - 1) {
            #pragma unroll
            for (int j = 0; j < 8; ++j)
                unsafeAtomicAdd(outp + j, src[j]);
        } else {
            *(float4*)(outp)     = *(const float4*)(src);
            *(float4*)(outp + 4) = *(const float4*)(src + 4);
        }
    }
}

// ---------------------------------------------------------------------------
// K3-MFMA: out = ssp(acc @ Wo1 + bo1) @ Wo2 + bo2. 64 atoms / block.
// ---------------------------------------------------------------------------
__global__ __launch_bounds__(256) void k_out_mfma(
        const float* __restrict__ acc_in,
        const short* __restrict__ Wo1T, const float* __restrict__ bo1,
        const short* __restrict__ Wo2T, const float* __restrict__ bo2,
        float* __restrict__ out) {
    __shared__ __attribute__((aligned(16))) char lds[64 * 136 * 2 * 2]; // 34816 B
    unsigned short* AsB = (unsigned short*)lds;                  // [64][136]
    unsigned short* O1B = (unsigned short*)(lds + 64 * 136 * 2); // [64][136]
    float* Of = (float*)lds;                                     // [64][132] alias

    const int t = threadIdx.x;
    const int r0g = blockIdx.x * 64;
    const int lane = t & 63, wv = t >> 6, q = lane >> 4, ln = lane & 15;

    // stage acc -> bf16 LDS
    #pragma unroll
    for (int i = 0; i < 4; ++i) {
        int idx = i * 256 + t;
        int row = idx >> 4, ch = idx & 15;
        float4 a = {0,0,0,0}, b = {0,0,0,0};
        if (r0g + row < NA) {
            const float* ap = acc_in + (size_t)(r0g + row) * FDIM + ch * 8;
            a = *(const float4*)ap;
            b = *(const float4*)(ap + 4);
        }
        short8 s = {f2bf(a.x), f2bf(a.y), f2bf(a.z), f2bf(a.w),
                    f2bf(b.x), f2bf(b.y), f2bf(b.z), f2bf(b.w)};
        *(short8*)(AsB + row * 136 + ch * 8) = s;
    }
    __syncthreads();

    // GEMM1: C1 = A @ Wo1T ; ssp(+bo1) -> bf16 O1B
    f32x4 c1[8];
    #pragma unroll
    for (int tt = 0; tt < 8; ++tt) c1[tt] = (f32x4){0.f, 0.f, 0.f, 0.f};
    #pragma unroll
    for (int kk = 0; kk < 4; ++kk) {
        short8 a = *(const short8*)(AsB + (16 * wv + ln) * 136 + kk * 32 + q * 8);
        #pragma unroll
        for (int tt = 0; tt < 8; ++tt) {
            short8 b = *(const short8*)(Wo1T + (16 * tt + ln) * FDIM + kk * 32 + q * 8);
            c1[tt] = __builtin_amdgcn_mfma_f32_16x16x32_bf16(a, b, c1[tt], 0, 0, 0);
        }
    }
    #pragma unroll
    for (int tt = 0; tt < 8; ++tt) {
        float bias = bo1[16 * tt + ln];
        #pragma unroll
        for (int r = 0; r < 4; ++r) {
            float v = ssp_f(c1[tt][r] + bias);
            O1B[(16 * wv + 4 * q + r) * 136 + 16 * tt + ln] = (unsigned short)f2bf(v);
        }
    }
    __syncthreads();

    // GEMM2: C2 = O1 @ Wo2T + bo2
    f32x4 c2[8];
    #pragma unroll
    for (int tt = 0; tt < 8; ++tt) c2[tt] = (f32x4){0.f, 0.f, 0.f, 0.f};
    #pragma unroll
    for (int kk = 0; kk < 4; ++kk) {
        short8 a = *(const short8*)(O1B + (16 * wv + ln) * 136 + kk * 32 + q * 8);
        #pragma unroll
        for (int tt = 0; tt < 8; ++tt) {
            short8 b = *(const short8*)(Wo2T + (16 * tt + ln) * FDIM + kk * 32 + q * 8);
            c2[tt] = __builtin_amdgcn_mfma_f32_16x16x32_bf16(a, b, c2[tt], 0, 0, 0);
        }
    }
    __syncthreads();   // all O1B reads done; Of overwrites lds

    #pragma unroll
    for (int tt = 0; tt < 8; ++tt) {
        float bias = bo2[16 * tt + ln];
        #pragma unroll
        for (int r = 0; r < 4; ++r)
            Of[(16 * wv + 4 * q + r) * 132 + 16 * tt + ln] = c2[tt][r] + bias;
    }
    __syncthreads();

    #pragma unroll
    for (int i = 0; i < 8; ++i) {
        int idx = i * 256 + t;
        int row = idx >> 5, ch = idx & 31;
        if (r0g + row < NA)
            *(float4*)(out + (size_t)(r0g + row) * FDIM + ch * 4) =
                *(const float4*)(Of + row * 132 + ch * 4);
    }
}

// ---------------------------------------------------------------------------
// fp32 fallback kernels (ws too small for sort+transpose buffers)
// ---------------------------------------------------------------------------
__global__ __launch_bounds__(256) void k_in_proj(const float* __restrict__ x,
                                                 const float* __restrict__ W,
                                                 float* __restrict__ h) {
    __shared__ float Xs[32 * 132];
    const int t  = threadIdx.x;
    const int r0g = blockIdx.x * 32;
    const float4* xv = (const float4*)(x + (size_t)r0g * FDIM);
    #pragma unroll
    for (int i = 0; i < 4; ++i) {
        int idx = t + i * 256;
        *(float4*)(&Xs[(idx >> 5) * 132 + (idx & 31) * 4]) = xv[idx];
    }
    __syncthreads();
    const int c0 = (t & 15) * 8;
    const int r0 = (t >> 4) * 2;
    float acc[2][8] = {};
    #pragma unroll 4
    for (int k = 0; k < FDIM; ++k) {
        float xa = Xs[r0 * 132 + k];
        float xb = Xs[(r0 + 1) * 132 + k];
        float4 w0 = *(const float4*)(W + k * FDIM + c0);
        float4 w1 = *(const float4*)(W + k * FDIM + c0 + 4);
        float wv[8] = {w0.x, w0.y, w0.z, w0.w, w1.x, w1.y, w1.z, w1.w};
        #pragma unroll
        for (int j = 0; j < 8; ++j) {
            acc[0][j] += xa * wv[j];
            acc[1][j] += xb * wv[j];
        }
    }
    #pragma unroll
    for (int i = 0; i < 2; ++i) {
        float4 o0 = {acc[i][0], acc[i][1], acc[i][2], acc[i][3]};
        float4 o1 = {acc[i][4], acc[i][5], acc[i][6], acc[i][7]};
        float* hp = h + (size_t)(r0g + r0 + i) * FDIM + c0;
        *(float4*)(hp) = o0;  *(float4*)(hp + 4) = o1;
    }
}

__global__ __launch_bounds__(256) void k_pairs(const int*   __restrict__ pl,
                                               const float* __restrict__ fij,
                                               const float* __restrict__ fcut,
                                               const float* __restrict__ h,
                                               const float* __restrict__ Wf1,
                                               const float* __restrict__ bf1,
                                               const float* __restrict__ Wf2,
                                               const float* __restrict__ bf2,
                                               float* __restrict__ acc_out) {
    __shared__ float Fs[64 * 36];
    __shared__ float Tmp[64 * 132];
    __shared__ int   pis[64], pjs[64];
    __shared__ float cuts[64];
    const int t  = threadIdx.x;
    const int p0 = blockIdx.x * 64;
    const float4* fv = (const float4*)(fij + (size_t)p0 * NRBF);
    #pragma unroll
    for (int i = 0; i < 2; ++i) {
        int idx = t + i * 256;
        *(float4*)(&Fs[(idx >> 3) * 36 + (idx & 7) * 4]) = fv[idx];
    }
    if (t < 64) {
        pis[t]  = pl[p0 + t];
        pjs[t]  = pl[NP + p0 + t];
        cuts[t] = fcut[p0 + t];
    }
    __syncthreads();
    const int c0 = (t & 15) * 8;
    const int r0 = (t >> 4) * 4;
    float a1[4][8] = {};
    #pragma unroll 4
    for (int k = 0; k < NRBF; ++k) {
        float4 w0 = *(const float4*)(Wf1 + k * FDIM + c0);
        float4 w1 = *(const float4*)(Wf1 + k * FDIM + c0 + 4);
        float wv[8] = {w0.x, w0.y, w0.z, w0.w, w1.x, w1.y, w1.z, w1.w};
        float xr[4];
        #pragma unroll
        for (int i = 0; i < 4; ++i) xr[i] = Fs[(r0 + i) * 36 + k];
        #pragma unroll
        for (int i = 0; i < 4; ++i)
            #pragma unroll
            for (int j = 0; j < 8; ++j)
                a1[i][j] += xr[i] * wv[j];
    }
    {
        float4 b0 = *(const float4*)(bf1 + c0);
        float4 b1 = *(const float4*)(bf1 + c0 + 4);
        float bv[8] = {b0.x, b0.y, b0.z, b0.w, b1.x, b1.y, b1.z, b1.w};
        #pragma unroll
        for (int i = 0; i < 4; ++i)
            #pragma unroll
            for (int j = 0; j < 8; ++j)
                Tmp[(r0 + i) * 132 + c0 + j] = ssp_f(a1[i][j] + bv[j]);
    }
    __syncthreads();
    float a2[4][8] = {};
    #pragma unroll 2
    for (int k = 0; k < FDIM; ++k) {
        float4 w0 = *(const float4*)(Wf2 + k * FDIM + c0);
        float4 w1 = *(const float4*)(Wf2 + k * FDIM + c0 + 4);
        float wv[8] = {w0.x, w0.y, w0.z, w0.w, w1.x, w1.y, w1.z, w1.w};
        float xr[4];
        #pragma unroll
        for (int i = 0; i < 4; ++i) xr[i] = Tmp[(r0 + i) * 132 + k];
        #pragma unroll
        for (int i = 0; i < 4; ++i)
            #pragma unroll
            for (int j = 0; j < 8; ++j)
                a2[i][j] += xr[i] * wv[j];
    }
    float4 b20 = *(const float4*)(bf2 + c0);
    float4 b21 = *(const float4*)(bf2 + c0 + 4);
    float bv[8] = {b20.x, b20.y, b20.z, b20.w, b21.x, b21.y, b21.z, b21.w};
    #pragma unroll
    for (int i = 0; i < 4; ++i) {
        int   p   = r0 + i;
        float cut = cuts[p];
        const float* hr = h + (size_t)pjs[p] * FDIM + c0;
        float4 h0 = *(const float4*)(hr);
        float4 h1 = *(const float4*)(hr + 4);
        float hv[8] = {h0.x, h0.y, h0.z, h0.w, h1.x, h1.y, h1.z, h1.w};
        float* outp = acc_out + (size_t)pis[p] * FDIM + c0;
        #pragma unroll
        for (int j = 0; j < 8; ++j)
            unsafeAtomicAdd(outp + j, (a2[i][j] + bv[j]) * cut * hv[j]);
    }
}

__global__ __launch_bounds__(256) void k_out(const float* __restrict__ acc_in,
                                             const float* __restrict__ Wo1,
                                             const float* __restrict__ bo1,
                                             const float* __restrict__ Wo2,
                                             const float* __restrict__ bo2,
                                             float* __restrict__ out) {
    __shared__ float As[32 * 132];
    __shared__ float O1[32 * 132];
    const int t   = threadIdx.x;
    const int r0g = blockIdx.x * 32;
    const float4* av = (const float4*)(acc_in + (size_t)r0g * FDIM);
    #pragma unroll
    for (int i = 0; i < 4; ++i) {
        int idx = t + i * 256;
        *(float4*)(&As[(idx >> 5) * 132 + (idx & 31) * 4]) = av[idx];
    }
    __syncthreads();
    const int c0 = (t & 15) * 8;
    const int r0 = (t >> 4) * 2;
    float acc[2][8] = {};
    #pragma unroll 4
    for (int k = 0; k < FDIM; ++k) {
        float xa = As[r0 * 132 + k];
        float xb = As[(r0 + 1) * 132 + k];
        float4 w0 = *(const float4*)(Wo1 + k * FDIM + c0);
        float4 w1 = *(const float4*)(Wo1 + k * FDIM + c0 + 4);
        float wv[8] = {w0.x, w0.y, w0.z, w0.w, w1.x, w1.y, w1.z, w1.w};
        #pragma unroll
        for (int j = 0; j < 8; ++j) {
            acc[0][j] += xa * wv[j];
            acc[1][j] += xb * wv[j];
        }
    }
    {
        float4 b0 = *(const float4*)(bo1 + c0);
        float4 b1 = *(const float4*)(bo1 + c0 + 4);
        float bv[8] = {b0.x, b0.y, b0.z, b0.w, b1.x, b1.y, b1.z, b1.w};
        #pragma unroll
        for (int i = 0; i < 2; ++i)
            #pragma unroll
            for (int j = 0; j < 8; ++j)
                O1[(r0 + i) * 132 + c0 + j] = ssp_f(acc[i][j] + bv[j]);
    }
    __syncthreads();
    float acc2[2][8] = {};
    #pragma unroll 4
    for (int k = 0; k < FDIM; ++k) {
        float xa = O1[r0 * 132 + k];
        float xb = O1[(r0 + 1) * 132 + k];
        float4 w0 = *(const float4*)(Wo2 + k * FDIM + c0);
        float4 w1 = *(const float4*)(Wo2 + k * FDIM + c0 + 4);
        float wv[8] = {w0.x, w0.y, w0.z, w0.w, w1.x, w1.y, w1.z, w1.w};
        #pragma unroll
        for (int j = 0; j < 8; ++j) {
            acc2[0][j] += xa * wv[j];
            acc2[1][j] += xb * wv[j];
        }
    }
    float4 b0 = *(const float4*)(bo2 + c0);
    float4 b1 = *(const float4*)(bo2 + c0 + 4);
    float bv[8] = {b0.x, b0.y, b0.z, b0.w, b1.x, b1.y, b1.z, b1.w};
    #pragma unroll
    for (int i = 0; i < 2; ++i) {
        float4 o0 = {acc2[i][0] + bv[0], acc2[i][1] + bv[1],
                     acc2[i][2] + bv[2], acc2[i][3] + bv[3]};
        float4 o1 = {acc2[i][4] + bv[4], acc2[i][5] + bv[5],
                     acc2[i][6] + bv[6], acc2[i][7] + bv[7]};
        float* op = out + (size_t)(r0g + r0 + i) * FDIM + c0;
        *(float4*)(op) = o0;  *(float4*)(op + 4) = o1;
    }
}

extern "C" void kernel_launch(void* const* d_in, const int* in_sizes, int n_in,
                              void* d_out, int out_size, void* d_ws, size_t ws_size,
                              hipStream_t stream) {
    const float* x    = (const float*)d_in[0];
    const int*   pl   = (const int*)  d_in[1];
    const float* fij  = (const float*)d_in[2];
    const float* fcut = (const float*)d_in[3];
    const float* W_in = (const float*)d_in[4];
    const float* Wf1  = (const float*)d_in[5];
    const float* bf1  = (const float*)d_in[6];
    const float* Wf2  = (const float*)d_in[7];
    const float* bf2  = (const float*)d_in[8];
    const float* Wo1  = (const float*)d_in[9];
    const float* bo1  = (const float*)d_in[10];
    const float* Wo2  = (const float*)d_in[11];
    const float* bo2  = (const float*)d_in[12];
    float* out = (float*)d_out;

    // ws layout (sorted path)
    char*  wsp   = (char*)d_ws;
    float* acc   = (float*)wsp;                              // NA*128 f32
    short* hB    = (short*)(acc + (size_t)NA * FDIM);        // NA*128 bf16
    int*   count = (int*)(hB + (size_t)NA * FDIM);           // NA int
    int*   base  = count + NA;                               // NA int
    int*   cursor= base + NA;                                // NA int
    int*   bsum  = cursor + NA;                              // 512 int
    int*   perm  = bsum + 512;                               // NP int
    short* Wf1T  = (short*)(perm + NP);                      // 128*32 bf16
    short* Wf2T  = Wf1T + 128 * 32;                          // 128*128 bf16
    short* Wo1T  = Wf2T + 128 * 128;
    short* Wo2T  = Wo1T + 128 * 128;
    short* WinT  = Wo2T + 128 * 128;

    const size_t needed = (size_t)NA * FDIM * 4              // acc
                        + (size_t)NA * FDIM * 2              // hB
                        + ((size_t)NA * 3 + 512 + NP) * 4
                        + (size_t)(128 * 32 + 4 * 128 * 128) * 2;
    const bool sorted_path = (ws_size >= needed);

    const int NB  = (NA + 255) / 256;   // 391 scan blocks
    const int NBA = (NA + 63) / 64;     // 1563 atom-tile blocks

    if (sorted_path) {
        hipMemsetAsync(acc, 0, (size_t)NA * FDIM * sizeof(float), stream);
        hipMemsetAsync(count, 0, (size_t)NA * sizeof(int), stream);
        k_prep   <<<64, 256, 0, stream>>>(Wf1, Wf2, Wo1, Wo2, W_in,
                                          Wf1T, Wf2T, Wo1T, Wo2T, WinT);
        k_in_proj_mfma<<<NBA, 256, 0, stream>>>(x, WinT, hB, pl, count);
        k_scan1  <<<NB, 256, 0, stream>>>(count, base, bsum);
        k_scan2  <<<1, 512, 0, stream>>>(bsum, NB);
        k_scan3  <<<NB, 256, 0, stream>>>(bsum, base, cursor);
        k_reorder<<<(NP + 255) / 256, 256, 0, stream>>>(pl, cursor, perm);
        k_pairs_mfma<<<NP / 64, 256, 0, stream>>>(perm, pl, fij, fcut, hB,
                                                  Wf1T, bf1, Wf2T, bf2, acc);
        k_out_mfma<<<NBA, 256, 0, stream>>>(acc, Wo1T, bo1, Wo2T, bo2, out);
    } else {
        float* hF   = (float*)wsp;
        float* accF = hF + (size_t)NA * FDIM;
        hipMemsetAsync(accF, 0, (size_t)NA * FDIM * sizeof(float), stream);
        k_in_proj<<<NA / 32, 256, 0, stream>>>(x, W_in, hF);
        k_pairs<<<NP / 64, 256, 0, stream>>>(pl, fij, fcut, hF,
                                             Wf1, bf1, Wf2, bf2, accF);
        k_out<<<NA / 32, 256, 0, stream>>>(accF, Wo1, bo1, Wo2, bo2, out);
    }
}

// Round 2
// 1157.976 us; speedup vs baseline: 1.1982x; 1.1982x over previous
//
#include <hip/hip_runtime.h>

#define NA   100000
#define NP   1600000
#define FDIM 128
#define NRBF 32
#define LN2  0.69314718055994530942f

typedef __attribute__((ext_vector_type(8))) short short8;  // 8 bf16 = 4 VGPRs
typedef __attribute__((ext_vector_type(4))) float f32x4;

// ShiftedSoftplus via hardware exp2/log2:
// softplus(x)-ln2 = max(x,0) + ln2*(log2(1 + 2^(-|x|*log2e)) - 1)
__device__ __forceinline__ float ssp_f(float v) {
    float e = __builtin_amdgcn_exp2f(fabsf(v) * -1.4426950408889634f);
    float l = __builtin_amdgcn_logf(1.0f + e);          // log2
    return fmaxf(v, 0.0f) + 0.6931471805599453f * (l - 1.0f);
}

// f32 -> bf16 with round-to-nearest-even
__device__ __forceinline__ short f2bf(float f) {
    union { float f; unsigned u; } v; v.f = f;
    unsigned r = v.u + 0x7FFF + ((v.u >> 16) & 1);
    return (short)(r >> 16);
}

// bf16 (as u16) -> f32
__device__ __forceinline__ float bf2f(unsigned short u) {
    union { unsigned u; float f; } v; v.u = ((unsigned)u) << 16;
    return v.f;
}

// ---------------------------------------------------------------------------
// K0: pre-transpose all weights to bf16 [n][k] in ws.
// ---------------------------------------------------------------------------
__global__ void k_prep(const float* __restrict__ Wf1, const float* __restrict__ Wf2,
                       const float* __restrict__ Wo1, const float* __restrict__ Wo2,
                       const float* __restrict__ Win,
                       short* __restrict__ Wf1T, short* __restrict__ Wf2T,
                       short* __restrict__ Wo1T, short* __restrict__ Wo2T,
                       short* __restrict__ WinT) {
    int i = blockIdx.x * 256 + threadIdx.x;          // 64 blocks -> 16384
    int n = i >> 7, k = i & 127;
    Wf2T[i] = f2bf(Wf2[k * FDIM + n]);
    Wo1T[i] = f2bf(Wo1[k * FDIM + n]);
    Wo2T[i] = f2bf(Wo2[k * FDIM + n]);
    WinT[i] = f2bf(Win[k * FDIM + n]);
    if (i < 128 * 32) {
        int n1 = i >> 5, k1 = i & 31;
        Wf1T[i] = f2bf(Wf1[k1 * FDIM + n1]);
    }
}

// ---------------------------------------------------------------------------
// K1-MFMA: h = x @ W_in (no bias), output bf16. 64 atoms / 256-thread block.
// Also computes a slice of the pair histogram (fused, hides under x staging).
// ---------------------------------------------------------------------------
__global__ __launch_bounds__(256) void k_in_proj_mfma(
        const float* __restrict__ x, const short* __restrict__ WinT,
        short* __restrict__ hB,
        const int* __restrict__ pl, int* __restrict__ count) {
    __shared__ __attribute__((aligned(16))) unsigned short XsB[64 * 136]; // 17408 B

    const int t = threadIdx.x;
    const int r0g = blockIdx.x * 64;
    const int lane = t & 63, wv = t >> 6, q = lane >> 4, ln = lane & 15;

    // fused histogram slice: NBA*1024 >= NP
    {
        int p = blockIdx.x * 1024 + t;
        #pragma unroll
        for (int i = 0; i < 4; ++i) {
            if (p < NP) atomicAdd(&count[pl[p]], 1);
            p += 256;
        }
    }

    // stage x tile -> bf16 LDS (row layout)
    #pragma unroll
    for (int i = 0; i < 4; ++i) {
        int idx = i * 256 + t;
        int row = idx >> 4, ch = idx & 15;             // 16 chunks of 8 floats
        float4 a = {0,0,0,0}, b = {0,0,0,0};
        if (r0g + row < NA) {
            const float* xp = x + (size_t)(r0g + row) * FDIM + ch * 8;
            a = *(const float4*)xp;
            b = *(const float4*)(xp + 4);
        }
        short8 s = {f2bf(a.x), f2bf(a.y), f2bf(a.z), f2bf(a.w),
                    f2bf(b.x), f2bf(b.y), f2bf(b.z), f2bf(b.w)};
        *(short8*)(XsB + row * 136 + ch * 8) = s;
    }
    __syncthreads();

    f32x4 c[8];
    #pragma unroll
    for (int tt = 0; tt < 8; ++tt) c[tt] = (f32x4){0.f, 0.f, 0.f, 0.f};
    #pragma unroll
    for (int kk = 0; kk < 4; ++kk) {
        short8 a = *(const short8*)(XsB + (16 * wv + ln) * 136 + kk * 32 + q * 8);
        #pragma unroll
        for (int tt = 0; tt < 8; ++tt) {
            short8 b = *(const short8*)(WinT + (16 * tt + ln) * FDIM + kk * 32 + q * 8);
            c[tt] = __builtin_amdgcn_mfma_f32_16x16x32_bf16(a, b, c[tt], 0, 0, 0);
        }
    }
    __syncthreads();   // XsB reads done; may overwrite with output

    #pragma unroll
    for (int tt = 0; tt < 8; ++tt)
        #pragma unroll
        for (int r = 0; r < 4; ++r)
            XsB[(16 * wv + 4 * q + r) * 136 + 16 * tt + ln] =
                (unsigned short)f2bf(c[tt][r]);
    __syncthreads();

    #pragma unroll
    for (int i = 0; i < 4; ++i) {
        int idx = i * 256 + t;
        int row = idx >> 4, ch = idx & 15;             // 16 short8 chunks/row
        if (r0g + row < NA)
            *(short8*)(hB + (size_t)(r0g + row) * FDIM + ch * 8) =
                *(const short8*)(XsB + row * 136 + ch * 8);
    }
}

// ---------------------------------------------------------------------------
// Sort pipeline: counting sort of pairs by idx_i (hist fused into K1).
// ---------------------------------------------------------------------------
__global__ __launch_bounds__(256) void k_scan1(const int* __restrict__ count,
                                               int* __restrict__ base,
                                               int* __restrict__ bsum) {
    __shared__ int sh[256];
    int i = blockIdx.x * 256 + threadIdx.x;
    int v = (i < NA) ? count[i] : 0;
    sh[threadIdx.x] = v;
    __syncthreads();
    for (int off = 1; off < 256; off <<= 1) {
        int add = (threadIdx.x >= off) ? sh[threadIdx.x - off] : 0;
        __syncthreads();
        sh[threadIdx.x] += add;
        __syncthreads();
    }
    if (i < NA) base[i] = sh[threadIdx.x] - v;     // exclusive
    if (threadIdx.x == 255) bsum[blockIdx.x] = sh[255];
}

__global__ __launch_bounds__(512) void k_scan2(int* __restrict__ bsum, int nb) {
    __shared__ int sh[512];
    int t = threadIdx.x;
    int v = (t < nb) ? bsum[t] : 0;
    sh[t] = v;
    __syncthreads();
    for (int off = 1; off < 512; off <<= 1) {
        int add = (t >= off) ? sh[t - off] : 0;
        __syncthreads();
        sh[t] += add;
        __syncthreads();
    }
    if (t < nb) bsum[t] = sh[t] - v;               // exclusive
}

__global__ void k_scan3(const int* __restrict__ bsum, int* __restrict__ base,
                        int* __restrict__ cursor) {
    int i = blockIdx.x * 256 + threadIdx.x;
    if (i < NA) {
        int b = base[i] + bsum[blockIdx.x];
        base[i]   = b;
        cursor[i] = b;
    }
}

__global__ void k_reorder(const int* __restrict__ pl, int* __restrict__ cursor,
                          int* __restrict__ perm) {
    int p = blockIdx.x * 256 + threadIdx.x;
    if (p < NP) {
        int pos = atomicAdd(&cursor[pl[p]], 1);
        perm[pos] = p;
    }
}

// ---------------------------------------------------------------------------
// K2-MFMA: fused filter network (bf16 MFMA) + gather + sorted LDS scatter.
// Latency-hiding restructure (T14):
//  * per-thread h gather chain (perm->pl->hB, 16B) issued at kernel start,
//    lands in registers; hidden under fij wait + both filter GEMMs.
//  * W_ij transposed through LDS but pulled into registers BEFORE SlotAcc
//    zeroing, so WB time-multiplexes the SlotAcc region: LDS 52.7->35.6 KB
//    -> 4 blocks/CU (occupancy ~28%->~47%).
//  * phase 3 is pure register FMA + LDS slot atomics (no memory waits).
// ---------------------------------------------------------------------------
__global__ __launch_bounds__(256, 4) void k_pairs_mfma(
        const int*   __restrict__ perm,
        const int*   __restrict__ pl,
        const float* __restrict__ fij,
        const float* __restrict__ fcut,
        const short* __restrict__ hB,
        const short* __restrict__ Wf1T,
        const float* __restrict__ bf1,
        const short* __restrict__ Wf2T,
        const float* __restrict__ bf2,
        float* __restrict__ acc_out) {
    // 34816 B region, triple-purpose:
    //   phase1-2 : TmpB = first 17408 B ([64][136] bf16)
    //   WB stage : WB   = second 17408 B ([64][136] bf16)
    //   phase3   : SlotAcc[64][136] f32 (zeroed only [0, nslots*136))
    __shared__ __attribute__((aligned(16))) float SlotAcc[64 * 136];
    unsigned short* TmpB = (unsigned short*)SlotAcc;
    unsigned short* WB   = (unsigned short*)SlotAcc + 64 * 136;
    __shared__ int   slots[64], slot_atom[64];
    __shared__ float cuts[64];
    __shared__ int   nslots_s;

    const int t    = threadIdx.x;
    const int p0   = blockIdx.x * 64;
    const int lane = t & 63;
    const int wv   = t >> 6;          // wave id = m-tile
    const int q    = lane >> 4;       // quad
    const int ln   = lane & 15;
    const int r0   = (t >> 4) * 4;    // phase-3 row group (4 sorted pairs)
    const int c0   = (t & 15) * 8;    // phase-3 channel group (8 contiguous)

    // ---- issue long-latency gathers first -------------------------------
    // fij rows for phase 1 (own perm entry; 4-way broadcast within wave)
    const int sp_self = perm[p0 + 16 * wv + ln];
    // h chain: perm -> pl(j) -> hB row 16B  (results used only in phase 3)
    int pp[4];
    #pragma unroll
    for (int r = 0; r < 4; ++r) pp[r] = perm[p0 + r0 + r];

    // wave 0: slot/ballot setup (independent loads, overlaps the above)
    if (t < 64) {
        int sp = perm[p0 + t];
        int ai = pl[sp];
        cuts[t] = fcut[sp];
        int prev = __shfl_up(ai, 1);
        bool head = (t == 0) || (ai != prev);
        unsigned long long mask = __ballot(head);
        int slot = __popcll(mask & ((2ULL << t) - 1)) - 1;
        slots[t] = slot;
        if (head) slot_atom[slot] = ai;
        if (t == 0) nslots_s = (int)__popcll(mask);
    }

    int aj[4];
    #pragma unroll
    for (int r = 0; r < 4; ++r) aj[r] = pl[NP + pp[r]];

    // ---- phase 1: C1 = F @ Wf1 (A built in-reg from gathered f_ij rows) ----
    short8 aF;
    {
        const float* fr = fij + (size_t)sp_self * NRBF + q * 8;
        float4 f0 = *(const float4*)(fr);
        float4 f1 = *(const float4*)(fr + 4);
        aF = (short8){f2bf(f0.x), f2bf(f0.y), f2bf(f0.z), f2bf(f0.w),
                      f2bf(f1.x), f2bf(f1.y), f2bf(f1.z), f2bf(f1.w)};
    }
    f32x4 c1[8];
    #pragma unroll
    for (int tt = 0; tt < 8; ++tt) {
        short8 b = *(const short8*)(Wf1T + (16 * tt + ln) * NRBF + q * 8);
        f32x4 z = {0.f, 0.f, 0.f, 0.f};
        c1[tt] = __builtin_amdgcn_mfma_f32_16x16x32_bf16(aF, b, z, 0, 0, 0);
    }

    // ssp + bias, C-layout -> TmpB[pair][k] bf16 (A-layout for phase 2)
    #pragma unroll
    for (int tt = 0; tt < 8; ++tt) {
        float bias = bf1[16 * tt + ln];
        #pragma unroll
        for (int r = 0; r < 4; ++r) {
            float v = ssp_f(c1[tt][r] + bias);
            TmpB[(16 * wv + 4 * q + r) * 136 + 16 * tt + ln] = (unsigned short)f2bf(v);
        }
    }

    // issue h-row gathers now (aj landed during phase 1); used in phase 3
    short8 hreg[4];
    #pragma unroll
    for (int r = 0; r < 4; ++r)
        hreg[r] = *(const short8*)(hB + (size_t)aj[r] * FDIM + c0);

    __syncthreads();   // B1: TmpB + wave0 setup visible

    const int nslots = nslots_s;

    // ---- phase 2: C2 = Tmp @ Wf2, 4 k-steps ----
    f32x4 c2[8];
    #pragma unroll
    for (int tt = 0; tt < 8; ++tt) c2[tt] = (f32x4){0.f, 0.f, 0.f, 0.f};
    #pragma unroll
    for (int kk = 0; kk < 4; ++kk) {
        short8 a = *(const short8*)(TmpB + (16 * wv + ln) * 136 + kk * 32 + q * 8);
        #pragma unroll
        for (int tt = 0; tt < 8; ++tt) {
            short8 b = *(const short8*)(Wf2T + (size_t)(16 * tt + ln) * FDIM + kk * 32 + q * 8);
            c2[tt] = __builtin_amdgcn_mfma_f32_16x16x32_bf16(a, b, c2[tt], 0, 0, 0);
        }
    }
    __syncthreads();   // B2: TmpB reads done; WB region free

    // ---- stage W_ij = (C2 + bf2) * cut -> WB (bf16, transposed) ----
    #pragma unroll
    for (int tt = 0; tt < 8; ++tt) {
        float bias = bf2[16 * tt + ln];
        #pragma unroll
        for (int r = 0; r < 4; ++r) {
            int row = 16 * wv + 4 * q + r;
            float v = (c2[tt][r] + bias) * cuts[row];
            WB[row * 136 + 16 * tt + ln] = (unsigned short)f2bf(v);
        }
    }
    __syncthreads();   // B3: WB visible

    // pull this thread's W block into registers (rows r0..r0+3, ch c0..c0+7)
    short8 wreg[4];
    #pragma unroll
    for (int r = 0; r < 4; ++r)
        wreg[r] = *(const short8*)(WB + (r0 + r) * 136 + c0);
    __syncthreads();   // B4: WB reads done; SlotAcc may be zeroed

    for (int i = t; i < nslots * 136; i += 256) SlotAcc[i] = 0.f;
    __syncthreads();   // B5: zero visible

    // ---- phase 3: pure register FMA + LDS slot accumulation ----
    {
        float run[8] = {};
        int cur = slots[r0];
        #pragma unroll
        for (int r = 0; r < 4; ++r) {
            int s = slots[r0 + r];
            if (s != cur) {
                #pragma unroll
                for (int j = 0; j < 8; ++j) {
                    atomicAdd(&SlotAcc[cur * 136 + c0 + j], run[j]);
                    run[j] = 0.f;
                }
                cur = s;
            }
            #pragma unroll
            for (int j = 0; j < 8; ++j)
                run[j] = fmaf(bf2f((unsigned short)wreg[r][j]),
                              bf2f((unsigned short)hreg[r][j]), run[j]);
        }
        #pragma unroll
        for (int j = 0; j < 8; ++j)
            atomicAdd(&SlotAcc[cur * 136 + c0 + j], run[j]);
    }
    __syncthreads();   // B6

    // ---- flush: interior slots exclusive -> plain stores; edges atomic ----
    for (int s = (t >> 4); s < nslots; s += 16) {
        float* outp = acc_out + (size_t)slot_atom[s] * FDIM + c0;
        const float* src = &SlotAcc[s * 136 + c0];
        if (s == 0 || s == nslots - 1) {
            #pragma unroll
            for (int j = 0; j < 8; ++j)
                unsafeAtomicAdd(outp + j, src[j]);
        } else {
            *(float4*)(outp)     = *(const float4*)(src);
            *(float4*)(outp + 4) = *(const float4*)(src + 4);
        }
    }
}

// ---------------------------------------------------------------------------
// K3-MFMA: out = ssp(acc @ Wo1 + bo1) @ Wo2 + bo2. 64 atoms / block.
// ---------------------------------------------------------------------------
__global__ __launch_bounds__(256) void k_out_mfma(
        const float* __restrict__ acc_in,
        const short* __restrict__ Wo1T, const float* __restrict__ bo1,
        const short* __restrict__ Wo2T, const float* __restrict__ bo2,
        float* __restrict__ out) {
    __shared__ __attribute__((aligned(16))) char lds[64 * 136 * 2 * 2]; // 34816 B
    unsigned short* AsB = (unsigned short*)lds;                  // [64][136]
    unsigned short* O1B = (unsigned short*)(lds + 64 * 136 * 2); // [64][136]
    float* Of = (float*)lds;                                     // [64][132] alias

    const int t = threadIdx.x;
    const int r0g = blockIdx.x * 64;
    const int lane = t & 63, wv = t >> 6, q = lane >> 4, ln = lane & 15;

    // stage acc -> bf16 LDS
    #pragma unroll
    for (int i = 0; i < 4; ++i) {
        int idx = i * 256 + t;
        int row = idx >> 4, ch = idx & 15;
        float4 a = {0,0,0,0}, b = {0,0,0,0};
        if (r0g + row < NA) {
            const float* ap = acc_in + (size_t)(r0g + row) * FDIM + ch * 8;
            a = *(const float4*)ap;
            b = *(const float4*)(ap + 4);
        }
        short8 s = {f2bf(a.x), f2bf(a.y), f2bf(a.z), f2bf(a.w),
                    f2bf(b.x), f2bf(b.y), f2bf(b.z), f2bf(b.w)};
        *(short8*)(AsB + row * 136 + ch * 8) = s;
    }
    __syncthreads();

    // GEMM1: C1 = A @ Wo1T ; ssp(+bo1) -> bf16 O1B
    f32x4 c1[8];
    #pragma unroll
    for (int tt = 0; tt < 8; ++tt) c1[tt] = (f32x4){0.f, 0.f, 0.f, 0.f};
    #pragma unroll
    for (int kk = 0; kk < 4; ++kk) {
        short8 a = *(const short8*)(AsB + (16 * wv + ln) * 136 + kk * 32 + q * 8);
        #pragma unroll
        for (int tt = 0; tt < 8; ++tt) {
            short8 b = *(const short8*)(Wo1T + (16 * tt + ln) * FDIM + kk * 32 + q * 8);
            c1[tt] = __builtin_amdgcn_mfma_f32_16x16x32_bf16(a, b, c1[tt], 0, 0, 0);
        }
    }
    #pragma unroll
    for (int tt = 0; tt < 8; ++tt) {
        float bias = bo1[16 * tt + ln];
        #pragma unroll
        for (int r = 0; r < 4; ++r) {
            float v = ssp_f(c1[tt][r] + bias);
            O1B[(16 * wv + 4 * q + r) * 136 + 16 * tt + ln] = (unsigned short)f2bf(v);
        }
    }
    __syncthreads();

    // GEMM2: C2 = O1 @ Wo2T + bo2
    f32x4 c2[8];
    #pragma unroll
    for (int tt = 0; tt < 8; ++tt) c2[tt] = (f32x4){0.f, 0.f, 0.f, 0.f};
    #pragma unroll
    for (int kk = 0; kk < 4; ++kk) {
        short8 a = *(const short8*)(O1B + (16 * wv + ln) * 136 + kk * 32 + q * 8);
        #pragma unroll
        for (int tt = 0; tt < 8; ++tt) {
            short8 b = *(const short8*)(Wo2T + (16 * tt + ln) * FDIM + kk * 32 + q * 8);
            c2[tt] = __builtin_amdgcn_mfma_f32_16x16x32_bf16(a, b, c2[tt], 0, 0, 0);
        }
    }
    __syncthreads();   // all O1B reads done; Of overwrites lds

    #pragma unroll
    for (int tt = 0; tt < 8; ++tt) {
        float bias = bo2[16 * tt + ln];
        #pragma unroll
        for (int r = 0; r < 4; ++r)
            Of[(16 * wv + 4 * q + r) * 132 + 16 * tt + ln] = c2[tt][r] + bias;
    }
    __syncthreads();

    #pragma unroll
    for (int i = 0; i < 8; ++i) {
        int idx = i * 256 + t;
        int row = idx >> 5, ch = idx & 31;
        if (r0g + row < NA)
            *(float4*)(out + (size_t)(r0g + row) * FDIM + ch * 4) =
                *(const float4*)(Of + row * 132 + ch * 4);
    }
}

// ---------------------------------------------------------------------------
// fp32 fallback kernels (ws too small for sort+transpose buffers)
// ---------------------------------------------------------------------------
__global__ __launch_bounds__(256) void k_in_proj(const float* __restrict__ x,
                                                 const float* __restrict__ W,
                                                 float* __restrict__ h) {
    __shared__ float Xs[32 * 132];
    const int t  = threadIdx.x;
    const int r0g = blockIdx.x * 32;
    const float4* xv = (const float4*)(x + (size_t)r0g * FDIM);
    #pragma unroll
    for (int i = 0; i < 4; ++i) {
        int idx = t + i * 256;
        *(float4*)(&Xs[(idx >> 5) * 132 + (idx & 31) * 4]) = xv[idx];
    }
    __syncthreads();
    const int c0 = (t & 15) * 8;
    const int r0 = (t >> 4) * 2;
    float acc[2][8] = {};
    #pragma unroll 4
    for (int k = 0; k < FDIM; ++k) {
        float xa = Xs[r0 * 132 + k];
        float xb = Xs[(r0 + 1) * 132 + k];
        float4 w0 = *(const float4*)(W + k * FDIM + c0);
        float4 w1 = *(const float4*)(W + k * FDIM + c0 + 4);
        float wv[8] = {w0.x, w0.y, w0.z, w0.w, w1.x, w1.y, w1.z, w1.w};
        #pragma unroll
        for (int j = 0; j < 8; ++j) {
            acc[0][j] += xa * wv[j];
            acc[1][j] += xb * wv[j];
        }
    }
    #pragma unroll
    for (int i = 0; i < 2; ++i) {
        float4 o0 = {acc[i][0], acc[i][1], acc[i][2], acc[i][3]};
        float4 o1 = {acc[i][4], acc[i][5], acc[i][6], acc[i][7]};
        float* hp = h + (size_t)(r0g + r0 + i) * FDIM + c0;
        *(float4*)(hp) = o0;  *(float4*)(hp + 4) = o1;
    }
}

__global__ __launch_bounds__(256) void k_pairs(const int*   __restrict__ pl,
                                               const float* __restrict__ fij,
                                               const float* __restrict__ fcut,
                                               const float* __restrict__ h,
                                               const float* __restrict__ Wf1,
                                               const float* __restrict__ bf1,
                                               const float* __restrict__ Wf2,
                                               const float* __restrict__ bf2,
                                               float* __restrict__ acc_out) {
    __shared__ float Fs[64 * 36];
    __shared__ float Tmp[64 * 132];
    __shared__ int   pis[64], pjs[64];
    __shared__ float cuts[64];
    const int t  = threadIdx.x;
    const int p0 = blockIdx.x * 64;
    const float4* fv = (const float4*)(fij + (size_t)p0 * NRBF);
    #pragma unroll
    for (int i = 0; i < 2; ++i) {
        int idx = t + i * 256;
        *(float4*)(&Fs[(idx >> 3) * 36 + (idx & 7) * 4]) = fv[idx];
    }
    if (t < 64) {
        pis[t]  = pl[p0 + t];
        pjs[t]  = pl[NP + p0 + t];
        cuts[t] = fcut[p0 + t];
    }
    __syncthreads();
    const int c0 = (t & 15) * 8;
    const int r0 = (t >> 4) * 4;
    float a1[4][8] = {};
    #pragma unroll 4
    for (int k = 0; k < NRBF; ++k) {
        float4 w0 = *(const float4*)(Wf1 + k * FDIM + c0);
        float4 w1 = *(const float4*)(Wf1 + k * FDIM + c0 + 4);
        float wv[8] = {w0.x, w0.y, w0.z, w0.w, w1.x, w1.y, w1.z, w1.w};
        float xr[4];
        #pragma unroll
        for (int i = 0; i < 4; ++i) xr[i] = Fs[(r0 + i) * 36 + k];
        #pragma unroll
        for (int i = 0; i < 4; ++i)
            #pragma unroll
            for (int j = 0; j < 8; ++j)
                a1[i][j] += xr[i] * wv[j];
    }
    {
        float4 b0 = *(const float4*)(bf1 + c0);
        float4 b1 = *(const float4*)(bf1 + c0 + 4);
        float bv[8] = {b0.x, b0.y, b0.z, b0.w, b1.x, b1.y, b1.z, b1.w};
        #pragma unroll
        for (int i = 0; i < 4; ++i)
            #pragma unroll
            for (int j = 0; j < 8; ++j)
                Tmp[(r0 + i) * 132 + c0 + j] = ssp_f(a1[i][j] + bv[j]);
    }
    __syncthreads();
    float a2[4][8] = {};
    #pragma unroll 2
    for (int k = 0; k < FDIM; ++k) {
        float4 w0 = *(const float4*)(Wf2 + k * FDIM + c0);
        float4 w1 = *(const float4*)(Wf2 + k * FDIM + c0 + 4);
        float wv[8] = {w0.x, w0.y, w0.z, w0.w, w1.x, w1.y, w1.z, w1.w};
        float xr[4];
        #pragma unroll
        for (int i = 0; i < 4; ++i) xr[i] = Tmp[(r0 + i) * 132 + k];
        #pragma unroll
        for (int i = 0; i < 4; ++i)
            #pragma unroll
            for (int j = 0; j < 8; ++j)
                a2[i][j] += xr[i] * wv[j];
    }
    float4 b20 = *(const float4*)(bf2 + c0);
    float4 b21 = *(const float4*)(bf2 + c0 + 4);
    float bv[8] = {b20.x, b20.y, b20.z, b20.w, b21.x, b21.y, b21.z, b21.w};
    #pragma unroll
    for (int i = 0; i < 4; ++i) {
        int   p   = r0 + i;
        float cut = cuts[p];
        const float* hr = h + (size_t)pjs[p] * FDIM + c0;
        float4 h0 = *(const float4*)(hr);
        float4 h1 = *(const float4*)(hr + 4);
        float hv[8] = {h0.x, h0.y, h0.z, h0.w, h1.x, h1.y, h1.z, h1.w};
        float* outp = acc_out + (size_t)pis[p] * FDIM + c0;
        #pragma unroll
        for (int j = 0; j < 8; ++j)
            unsafeAtomicAdd(outp + j, (a2[i][j] + bv[j]) * cut * hv[j]);
    }
}

__global__ __launch_bounds__(256) void k_out(const float* __restrict__ acc_in,
                                             const float* __restrict__ Wo1,
                                             const float* __restrict__ bo1,
                                             const float* __restrict__ Wo2,
                                             const float* __restrict__ bo2,
                                             float* __restrict__ out) {
    __shared__ float As[32 * 132];
    __shared__ float O1[32 * 132];
    const int t   = threadIdx.x;
    const int r0g = blockIdx.x * 32;
    const float4* av = (const float4*)(acc_in + (size_t)r0g * FDIM);
    #pragma unroll
    for (int i = 0; i < 4; ++i) {
        int idx = t + i * 256;
        *(float4*)(&As[(idx >> 5) * 132 + (idx & 31) * 4]) = av[idx];
    }
    __syncthreads();
    const int c0 = (t & 15) * 8;
    const int r0 = (t >> 4) * 2;
    float acc[2][8] = {};
    #pragma unroll 4
    for (int k = 0; k < FDIM; ++k) {
        float xa = As[r0 * 132 + k];
        float xb = As[(r0 + 1) * 132 + k];
        float4 w0 = *(const float4*)(Wo1 + k * FDIM + c0);
        float4 w1 = *(const float4*)(Wo1 + k * FDIM + c0 + 4);
        float wv[8] = {w0.x, w0.y, w0.z, w0.w, w1.x, w1.y, w1.z, w1.w};
        #pragma unroll
        for (int j = 0; j < 8; ++j) {
            acc[0][j] += xa * wv[j];
            acc[1][j] += xb * wv[j];
        }
    }
    {
        float4 b0 = *(const float4*)(bo1 + c0);
        float4 b1 = *(const float4*)(bo1 + c0 + 4);
        float bv[8] = {b0.x, b0.y, b0.z, b0.w, b1.x, b1.y, b1.z, b1.w};
        #pragma unroll
        for (int i = 0; i < 2; ++i)
            #pragma unroll
            for (int j = 0; j < 8; ++j)
                O1[(r0 + i) * 132 + c0 + j] = ssp_f(acc[i][j] + bv[j]);
    }
    __syncthreads();
    float acc2[2][8] = {};
    #pragma unroll 4
    for (int k = 0; k < FDIM; ++k) {
        float xa = O1[r0 * 132 + k];
        float xb = O1[(r0 + 1) * 132 + k];
        float4 w0 = *(const float4*)(Wo2 + k * FDIM + c0);
        float4 w1 = *(const float4*)(Wo2 + k * FDIM + c0 + 4);
        float wv[8] = {w0.x, w0.y, w0.z, w0.w, w1.x, w1.y, w1.z, w1.w};
        #pragma unroll
        for (int j = 0; j < 8; ++j) {
            acc2[0][j] += xa * wv[j];
            acc2[1][j] += xb * wv[j];
        }
    }
    float4 b0 = *(const float4*)(bo2 + c0);
    float4 b1 = *(const float4*)(bo2 + c0 + 4);
    float bv[8] = {b0.x, b0.y, b0.z, b0.w, b1.x, b1.y, b1.z, b1.w};
    #pragma unroll
    for (int i = 0; i < 2; ++i) {
        float4 o0 = {acc2[i][0] + bv[0], acc2[i][1] + bv[1],
                     acc2[i][2] + bv[2], acc2[i][3] + bv[3]};
        float4 o1 = {acc2[i][4] + bv[4], acc2[i][5] + bv[5],
                     acc2[i][6] + bv[6], acc2[i][7] + bv[7]};
        float* op = out + (size_t)(r0g + r0 + i) * FDIM + c0;
        *(float4*)(op) = o0;  *(float4*)(op + 4) = o1;
    }
}

extern "C" void kernel_launch(void* const* d_in, const int* in_sizes, int n_in,
                              void* d_out, int out_size, void* d_ws, size_t ws_size,
                              hipStream_t stream) {
    const float* x    = (const float*)d_in[0];
    const int*   pl   = (const int*)  d_in[1];
    const float* fij  = (const float*)d_in[2];
    const float* fcut = (const float*)d_in[3];
    const float* W_in = (const float*)d_in[4];
    const float* Wf1  = (const float*)d_in[5];
    const float* bf1  = (const float*)d_in[6];
    const float* Wf2  = (const float*)d_in[7];
    const float* bf2  = (const float*)d_in[8];
    const float* Wo1  = (const float*)d_in[9];
    const float* bo1  = (const float*)d_in[10];
    const float* Wo2  = (const float*)d_in[11];
    const float* bo2  = (const float*)d_in[12];
    float* out = (float*)d_out;

    // ws layout (sorted path)
    char*  wsp   = (char*)d_ws;
    float* acc   = (float*)wsp;                              // NA*128 f32
    short* hB    = (short*)(acc + (size_t)NA * FDIM);        // NA*128 bf16
    int*   count = (int*)(hB + (size_t)NA * FDIM);           // NA int
    int*   base  = count + NA;                               // NA int
    int*   cursor= base + NA;                                // NA int
    int*   bsum  = cursor + NA;                              // 512 int
    int*   perm  = bsum + 512;                               // NP int
    short* Wf1T  = (short*)(perm + NP);                      // 128*32 bf16
    short* Wf2T  = Wf1T + 128 * 32;                          // 128*128 bf16
    short* Wo1T  = Wf2T + 128 * 128;
    short* Wo2T  = Wo1T + 128 * 128;
    short* WinT  = Wo2T + 128 * 128;

    const size_t needed = (size_t)NA * FDIM * 4              // acc
                        + (size_t)NA * FDIM * 2              // hB
                        + ((size_t)NA * 3 + 512 + NP) * 4
                        + (size_t)(128 * 32 + 4 * 128 * 128) * 2;
    const bool sorted_path = (ws_size >= needed);

    const int NB  = (NA + 255) / 256;   // 391 scan blocks
    const int NBA = (NA + 63) / 64;     // 1563 atom-tile blocks

    if (sorted_path) {
        hipMemsetAsync(acc, 0, (size_t)NA * FDIM * sizeof(float), stream);
        hipMemsetAsync(count, 0, (size_t)NA * sizeof(int), stream);
        k_prep   <<<64, 256, 0, stream>>>(Wf1, Wf2, Wo1, Wo2, W_in,
                                          Wf1T, Wf2T, Wo1T, Wo2T, WinT);
        k_in_proj_mfma<<<NBA, 256, 0, stream>>>(x, WinT, hB, pl, count);
        k_scan1  <<<NB, 256, 0, stream>>>(count, base, bsum);
        k_scan2  <<<1, 512, 0, stream>>>(bsum, NB);
        k_scan3  <<<NB, 256, 0, stream>>>(bsum, base, cursor);
        k_reorder<<<(NP + 255) / 256, 256, 0, stream>>>(pl, cursor, perm);
        k_pairs_mfma<<<NP / 64, 256, 0, stream>>>(perm, pl, fij, fcut, hB,
                                                  Wf1T, bf1, Wf2T, bf2, acc);
        k_out_mfma<<<NBA, 256, 0, stream>>>(acc, Wo1T, bo1, Wo2T, bo2, out);
    } else {
        float* hF   = (float*)wsp;
        float* accF = hF + (size_t)NA * FDIM;
        hipMemsetAsync(accF, 0, (size_t)NA * FDIM * sizeof(float), stream);
        k_in_proj<<<NA / 32, 256, 0, stream>>>(x, W_in, hF);
        k_pairs<<<NP / 64, 256, 0, stream>>>(pl, fij, fcut, hF,
                                             Wf1, bf1, Wf2, bf2, accF);
        k_out<<<NA / 32, 256, 0, stream>>>(accF, Wo1, bo1, Wo2, bo2, out);
    }
}